// Round 1
// 204.724 us; speedup vs baseline: 1.7375x; 1.7375x over previous
//
#include <hip/hip_runtime.h>
#include <hip/hip_bf16.h>

typedef __hip_bfloat16 bf16;
typedef __attribute__((ext_vector_type(8))) short short8;   // MFMA A/B frag (8 bf16)
typedef __attribute__((ext_vector_type(4))) float floatx4;  // MFMA C/D frag
typedef __attribute__((ext_vector_type(4))) short s16x4;

#define NE 524288
#define NA 16384
#define E  128       // edges per block (edge kernel), 8 waves
#define AG 32        // agents per block (agent kernel)
#define S1 260       // LDS act row stride (shorts)
#define SH3 68       // h3 overlay row stride (floats)

__device__ __forceinline__ float ld(const void* p, long i, int f32) {
    return f32 ? ((const float*)p)[i] : __bfloat162float(((const bf16*)p)[i]);
}
__device__ __forceinline__ short f2bs(float f) {
    bf16 h = __float2bfloat16(f);
    return *(short*)&h;
}
__device__ __forceinline__ float bs2f(short s) {
    union { unsigned u; float f; } c;
    c.u = ((unsigned)(unsigned short)s) << 16;
    return c.f;
}
// pack 2 floats -> 2 bf16 in one dword (a = low/even n, b = high/odd n)
__device__ __forceinline__ unsigned pk(float a, float b) {
    return ((unsigned)(unsigned short)f2bs(b) << 16) | (unsigned)(unsigned short)f2bs(a);
}

// ---------------------------------------------------------------------------
// Weight prep (dtype detector fused in). Edge-MLP weights are packed in exact
// per-(wave,ks,nt,lane) MFMA fragment order so every weight load in the edge
// kernel is ONE fully-coalesced 1 KB global_load_dwordx4:
//   Wp1P[((w*2+nt)*64 + lane)*8 + j]           (8 waves x 2 nt, K padded to 32)
//   Wp2P[(((w*8+ks)*2+nt)*64 + lane)*8 + j]    (8 waves x 8 ks x 2 nt)
//   Wp3P[((w*8+ks)*64 + lane)*8 + j]           (8 waves: (mh,ns) N-split, dup'd)
// Agent-MLP weights stay n-major [n][k] (unchanged). Biases + Wr3 to f32.
// ---------------------------------------------------------------------------
__global__ void prep_weights_kernel(
    const void* __restrict__ Wp1, const void* __restrict__ bp1,
    const void* __restrict__ Wp2, const void* __restrict__ bp2,
    const void* __restrict__ Wp3, const void* __restrict__ bp3,
    const void* __restrict__ Wr1, const void* __restrict__ br1,
    const void* __restrict__ Wr2, const void* __restrict__ br2,
    const void* __restrict__ Wr3, const void* __restrict__ br3,
    short* __restrict__ Wp1P, short* __restrict__ Wp2P, short* __restrict__ Wp3P,
    short* __restrict__ Wr1T,  short* __restrict__ Wr2T,
    float* __restrict__ bp1f, float* __restrict__ bp2f, float* __restrict__ bp3f,
    float* __restrict__ br1f, float* __restrict__ br2f,
    float* __restrict__ Wr3f, float* __restrict__ br3f,
    int* __restrict__ flag)
{
    __shared__ int sflag;
    if (threadIdx.x < 64) {
        const unsigned short* w = (const unsigned short*)Wp2;
        int bad = 0;
        for (int i = threadIdx.x; i < 1024; i += 64) {
            const int e = (w[i] >> 7) & 0xFF;
            if (e >= 131) bad = 1;                // |v|>=16 / inf / nan -> f32 bits
        }
        const unsigned long long m = __ballot(bad);
        if (threadIdx.x == 0) {
            sflag = (m != 0ull) ? 1 : 0;
            if (blockIdx.x == 0) *flag = sflag;
        }
    }
    __syncthreads();
    const int f32 = sflag;

    const int stride = gridDim.x * blockDim.x;
    for (int i = blockIdx.x * blockDim.x + threadIdx.x; i < 190018; i += stride) {
        if (i < 65536) {                       // Wp2P packed frags
            const int j = i & 7, lane = (i >> 3) & 63;
            const int nt = (i >> 9) & 1, ks = (i >> 10) & 7, w = (i >> 13) & 7;
            const int n = w * 32 + nt * 16 + (lane & 15);
            const int k = ks * 32 + (lane >> 4) * 8 + j;
            Wp2P[i] = f2bs(ld(Wp2, (long)k * 256 + n, f32));
        } else if (i < 98304) {                // Wp3P packed frags (N-split, dup per mh)
            const int ii = i - 65536;
            const int j = ii & 7, lane = (ii >> 3) & 63;
            const int ks = (ii >> 9) & 7, w = (ii >> 12) & 7;
            const int n = (w & 3) * 16 + (lane & 15);
            const int k = ks * 32 + (lane >> 4) * 8 + j;
            Wp3P[ii] = f2bs(ld(Wp3, (long)k * 64 + n, f32));
        } else if (i < 106496) {               // Wp1P packed frags, zero-pad k>=4
            const int ii = i - 98304;
            const int j = ii & 7, lane = (ii >> 3) & 63;
            const int nt = (ii >> 9) & 1, w = (ii >> 10) & 7;
            const int n = w * 32 + nt * 16 + (lane & 15);
            const int k = (lane >> 4) * 8 + j;
            Wp1P[ii] = (k < 4) ? f2bs(ld(Wp1, (long)k * 256 + n, f32)) : (short)0;
        } else if (i < 122880) {               // Wr1T[n][k=64]
            const int jj = i - 106496, n = jj >> 6, k = jj & 63;
            Wr1T[jj] = f2bs(ld(Wr1, (long)k * 256 + n, f32));
        } else if (i < 188416) {               // Wr2T[n][k=256]
            const int jj = i - 122880, n = jj >> 8, k = jj & 255;
            Wr2T[jj] = f2bs(ld(Wr2, (long)k * 256 + n, f32));
        } else if (i < 188672) { bp1f[i - 188416] = ld(bp1, i - 188416, f32); }
        else if (i < 188928) { bp2f[i - 188672] = ld(bp2, i - 188672, f32); }
        else if (i < 188992) { bp3f[i - 188928] = ld(bp3, i - 188928, f32); }
        else if (i < 189248) { br1f[i - 188992] = ld(br1, i - 188992, f32); }
        else if (i < 189504) { br2f[i - 189248] = ld(br2, i - 189248, f32); }
        else if (i < 190016) { Wr3f[i - 189504] = ld(Wr3, i - 189504, f32); }
        else                 { br3f[i - 190016] = ld(br3, i - 190016, f32); }
    }
}

// ---------------------------------------------------------------------------
// Edge MLP: 128 edges/block, 8 waves (512 thr). Swapped operands (weights=A,
// activations=B). Waves split N 8-way (32 features) in layers 1-2; layer 3
// splits (M-half x N-quarter). All weight loads are coalesced 1 KB frags.
// VGPR budget kept <=128 (16 waves/CU with 68 KB LDS -> 2 blocks/CU).
// ---------------------------------------------------------------------------
__global__ __launch_bounds__(512, 4) void edge_mlp_kernel(
    const void* __restrict__ ef, const int* __restrict__ ids,
    const short* __restrict__ Wp1P, const float* __restrict__ bp1f,
    const short* __restrict__ Wp2P, const float* __restrict__ bp2f,
    const short* __restrict__ Wp3P, const float* __restrict__ bp3f,
    float* __restrict__ agg, float* __restrict__ bar,
    const int* __restrict__ flag)
{
    __shared__ __align__(16) short hs[E * S1];     // 66.6 KB: h1, h2, then h3 overlay
    __shared__ float cb[E][2];
    __shared__ int   sid[E];

    const int t = threadIdx.x;
    const long e0 = (long)blockIdx.x * E;
    const int f32 = *flag;
    const int wave = t >> 6, lane = t & 63, quad = lane >> 4, ln = lane & 15;
    const int nw = wave * 32;                      // feature base, layers 1-2

    if (t < E) {
        sid[t] = ids[e0 + t];
        const float px = ld(ef, (e0 + t) * 4 + 0, f32);
        const float py = ld(ef, (e0 + t) * 4 + 1, f32);
        const float d = sqrtf(px * px + py * py);
        const float inv = 1.0f / (d * (d - 0.18f));
        cb[t][0] = -px * inv;
        cb[t][1] = -py * inv;
    }

    // ---- layer 1: h1 = relu(x @ Wp1 + bp1) ----
    {
        short8 b[8];                       // B-frags: edges mt*16+ln (quad 0 holds k<4)
        #pragma unroll
        for (int mt = 0; mt < 8; ++mt) {
            short8 v = {};
            if (quad == 0) {
                const long e = e0 + mt * 16 + ln;
                if (f32) {
                    const float4 x = ((const float4*)ef)[e];
                    v[0] = f2bs(x.x); v[1] = f2bs(x.y); v[2] = f2bs(x.z); v[3] = f2bs(x.w);
                } else {
                    const int2 x = ((const int2*)ef)[e];
                    v[0] = (short)(x.x & 0xffff); v[1] = (short)((unsigned)x.x >> 16);
                    v[2] = (short)(x.y & 0xffff); v[3] = (short)((unsigned)x.y >> 16);
                }
            }
            b[mt] = v;
        }
        floatx4 acc[8][2];                 // [mt][nt], init = bias rows
        #pragma unroll
        for (int nt = 0; nt < 2; ++nt) {
            const float4 bv = *(const float4*)&bp1f[nw + nt * 16 + quad * 4];
            const floatx4 bi = { bv.x, bv.y, bv.z, bv.w };
            #pragma unroll
            for (int mt = 0; mt < 8; ++mt) acc[mt][nt] = bi;
        }
        #pragma unroll
        for (int nt = 0; nt < 2; ++nt) {
            const short8 a = *(const short8*)&Wp1P[((wave * 2 + nt) * 64 + lane) * 8];
            #pragma unroll
            for (int mt = 0; mt < 8; ++mt)
                acc[mt][nt] = __builtin_amdgcn_mfma_f32_16x16x32_bf16(a, b[mt], acc[mt][nt], 0, 0, 0);
        }
        #pragma unroll
        for (int mt = 0; mt < 8; ++mt)
            #pragma unroll
            for (int nt = 0; nt < 2; ++nt) {
                const floatx4 v = acc[mt][nt];
                uint2 w;
                w.x = pk(fmaxf(v[0], 0.f), fmaxf(v[1], 0.f));
                w.y = pk(fmaxf(v[2], 0.f), fmaxf(v[3], 0.f));
                *(uint2*)&hs[(mt * 16 + ln) * S1 + nw + nt * 16 + quad * 4] = w;
            }
    }
    __syncthreads();

    // ---- layer 2: h2 = relu(h1 @ Wp2 + bp2); coalesced frags, depth-1 prefetch ----
    {
        floatx4 acc[8][2];
        #pragma unroll
        for (int nt = 0; nt < 2; ++nt) {
            const float4 bv = *(const float4*)&bp2f[nw + nt * 16 + quad * 4];
            const floatx4 bi = { bv.x, bv.y, bv.z, bv.w };
            #pragma unroll
            for (int mt = 0; mt < 8; ++mt) acc[mt][nt] = bi;
        }
        short8 wcur[2], wnxt[2];
        #pragma unroll
        for (int nt = 0; nt < 2; ++nt)
            wcur[nt] = *(const short8*)&Wp2P[(((wave * 8 + 0) * 2 + nt) * 64 + lane) * 8];
        #pragma unroll
        for (int ks = 0; ks < 8; ++ks) {
            if (ks < 7) {
                #pragma unroll
                for (int nt = 0; nt < 2; ++nt)
                    wnxt[nt] = *(const short8*)&Wp2P[(((wave * 8 + ks + 1) * 2 + nt) * 64 + lane) * 8];
            }
            #pragma unroll
            for (int mh = 0; mh < 2; ++mh) {       // mt chunks of 4 keep VGPR <= 128
                short8 b[4];
                #pragma unroll
                for (int m4 = 0; m4 < 4; ++m4)
                    b[m4] = *(const short8*)&hs[((mh * 4 + m4) * 16 + ln) * S1 + ks * 32 + quad * 8];
                #pragma unroll
                for (int m4 = 0; m4 < 4; ++m4)
                    #pragma unroll
                    for (int nt = 0; nt < 2; ++nt)
                        acc[mh * 4 + m4][nt] = __builtin_amdgcn_mfma_f32_16x16x32_bf16(wcur[nt], b[m4], acc[mh * 4 + m4][nt], 0, 0, 0);
            }
            #pragma unroll
            for (int nt = 0; nt < 2; ++nt) wcur[nt] = wnxt[nt];
        }
        __syncthreads();   // all h1 reads complete before overwrite
        #pragma unroll
        for (int mt = 0; mt < 8; ++mt)
            #pragma unroll
            for (int nt = 0; nt < 2; ++nt) {
                const floatx4 v = acc[mt][nt];
                uint2 w;
                w.x = pk(fmaxf(v[0], 0.f), fmaxf(v[1], 0.f));
                w.y = pk(fmaxf(v[2], 0.f), fmaxf(v[3], 0.f));
                *(uint2*)&hs[(mt * 16 + ln) * S1 + nw + nt * 16 + quad * 4] = w;
            }
    }
    __syncthreads();

    // ---- layer 3: h3 = h2 @ Wp3 + bp3; wave = (M-half mh, N-quarter ns) ----
    const int me = (wave >> 2) * 64;               // edge base (64 edges)
    const int fb = (wave & 3) * 16;                // feature base (16 features)
    floatx4 acc3[4];
    {
        const float4 bv = *(const float4*)&bp3f[fb + quad * 4];
        const floatx4 bi = { bv.x, bv.y, bv.z, bv.w };
        #pragma unroll
        for (int mt = 0; mt < 4; ++mt) acc3[mt] = bi;
        short8 w3 = *(const short8*)&Wp3P[((wave * 8 + 0) * 64 + lane) * 8];
        #pragma unroll
        for (int ks = 0; ks < 8; ++ks) {
            short8 wn = w3;
            if (ks < 7)
                wn = *(const short8*)&Wp3P[((wave * 8 + ks + 1) * 64 + lane) * 8];
            #pragma unroll
            for (int mt = 0; mt < 4; ++mt) {
                const short8 b = *(const short8*)&hs[(me + mt * 16 + ln) * S1 + ks * 32 + quad * 8];
                acc3[mt] = __builtin_amdgcn_mfma_f32_16x16x32_bf16(w3, b, acc3[mt], 0, 0, 0);
            }
            w3 = wn;
        }
    }
    __syncthreads();       // every wave finished reading h2 before overlay write
    float* h3f = (float*)hs;                       // f32 overlay [128][SH3]
    #pragma unroll
    for (int mt = 0; mt < 4; ++mt) {
        float4 v = { acc3[mt][0], acc3[mt][1], acc3[mt][2], acc3[mt][3] };
        *(float4*)&h3f[(me + mt * 16 + ln) * SH3 + fb + quad * 4] = v;
    }
    __syncthreads();

    // ---- scatter: each wave handles its own 16-edge window (ids sorted) ----
    {
        const int w0 = wave * 16;
        const int f = lane;                     // feature 0..63
        int cur = sid[w0];
        float local = h3f[w0 * SH3 + f];
        #pragma unroll
        for (int e = 1; e < 16; ++e) {
            const int id = sid[w0 + e];
            const float v = h3f[(w0 + e) * SH3 + f];
            if (id == cur) local += v;
            else { atomicAdd(&agg[(long)cur * 64 + f], local); cur = id; local = v; }
        }
        atomicAdd(&agg[(long)cur * 64 + f], local);

        if (lane < 2) {
            int c2 = sid[w0];
            float l2 = cb[w0][lane];
            #pragma unroll
            for (int e = 1; e < 16; ++e) {
                const int id = sid[w0 + e];
                const float v = cb[w0 + e][lane];
                if (id == c2) l2 += v;
                else { atomicAdd(&bar[c2 * 2 + lane], l2); c2 = id; l2 = v; }
            }
            atomicAdd(&bar[c2 * 2 + lane], l2);
        }
    }
}

// ---------------------------------------------------------------------------
// Agent MLP, all-MFMA, swapped operands. 32 agents/block, 512 blocks.
// ---------------------------------------------------------------------------
__global__ __launch_bounds__(256, 2) void agent_mlp_kernel(
    const float* __restrict__ agg, const float* __restrict__ bar,
    const short* __restrict__ Wr1T, const float* __restrict__ br1f,
    const short* __restrict__ Wr2T, const float* __restrict__ br2f,
    const float* __restrict__ Wr3f, const float* __restrict__ br3f,
    void* __restrict__ out, const int* __restrict__ flag)
{
    __shared__ __align__(16) short ha[AG * 68];    // bf16 agg (4.4 KB)
    __shared__ __align__(16) short hs[AG * S1];    // r1, then r2 (16.6 KB)
    __shared__ float part[8][AG][2];

    const int t = threadIdx.x;
    const int a0 = blockIdx.x * AG;
    const int f32 = *flag;
    const int wave = t >> 6, lane = t & 63, quad = lane >> 4, ln = lane & 15;
    const int nb = wave * 64;

    #pragma unroll
    for (int i = 0; i < 2; ++i) {
        const float4 x = ((const float4*)agg)[(long)blockIdx.x * 512 + i * 256 + t];
        const int idx4 = (i * 256 + t) * 4;
        s16x4 v = { f2bs(x.x), f2bs(x.y), f2bs(x.z), f2bs(x.w) };
        *(s16x4*)&ha[(idx4 >> 6) * 68 + (idx4 & 63)] = v;
    }
    __syncthreads();

    // ---- r1 = relu(a @ Wr1 + br1), K=64, M=32 ----
    {
        floatx4 acc[2][4];
        #pragma unroll
        for (int nt = 0; nt < 4; ++nt) {
            const float4 bv = *(const float4*)&br1f[nb + nt * 16 + quad * 4];
            const floatx4 bi = { bv.x, bv.y, bv.z, bv.w };
            #pragma unroll
            for (int mt = 0; mt < 2; ++mt) acc[mt][nt] = bi;
        }
        #pragma unroll
        for (int ks = 0; ks < 2; ++ks) {
            short8 b[2], a[4];
            #pragma unroll
            for (int mt = 0; mt < 2; ++mt)
                b[mt] = *(const short8*)&ha[(mt * 16 + ln) * 68 + ks * 32 + quad * 8];
            #pragma unroll
            for (int nt = 0; nt < 4; ++nt)
                a[nt] = *(const short8*)&Wr1T[(nb + nt * 16 + ln) * 64 + ks * 32 + quad * 8];
            #pragma unroll
            for (int mt = 0; mt < 2; ++mt)
                #pragma unroll
                for (int nt = 0; nt < 4; ++nt)
                    acc[mt][nt] = __builtin_amdgcn_mfma_f32_16x16x32_bf16(a[nt], b[mt], acc[mt][nt], 0, 0, 0);
        }
        #pragma unroll
        for (int mt = 0; mt < 2; ++mt)
            #pragma unroll
            for (int nt = 0; nt < 4; ++nt) {
                const floatx4 v = acc[mt][nt];
                uint2 w;
                w.x = pk(fmaxf(v[0], 0.f), fmaxf(v[1], 0.f));
                w.y = pk(fmaxf(v[2], 0.f), fmaxf(v[3], 0.f));
                *(uint2*)&hs[(mt * 16 + ln) * S1 + nb + nt * 16 + quad * 4] = w;
            }
    }
    __syncthreads();

    // ---- r2 = relu(r1 @ Wr2 + br2), K=256, single-buffer ----
    {
        floatx4 acc[2][4];
        #pragma unroll
        for (int nt = 0; nt < 4; ++nt) {
            const float4 bv = *(const float4*)&br2f[nb + nt * 16 + quad * 4];
            const floatx4 bi = { bv.x, bv.y, bv.z, bv.w };
            #pragma unroll
            for (int mt = 0; mt < 2; ++mt) acc[mt][nt] = bi;
        }
        short8 wcur[4], wnxt[4];
        #pragma unroll
        for (int nt = 0; nt < 4; ++nt)
            wcur[nt] = *(const short8*)&Wr2T[(nb + nt * 16 + ln) * 256 + quad * 8];
        #pragma unroll
        for (int ks = 0; ks < 8; ++ks) {
            if (ks < 7) {
                #pragma unroll
                for (int nt = 0; nt < 4; ++nt)
                    wnxt[nt] = *(const short8*)&Wr2T[(nb + nt * 16 + ln) * 256 + (ks + 1) * 32 + quad * 8];
            }
            short8 b[2];
            #pragma unroll
            for (int mt = 0; mt < 2; ++mt)
                b[mt] = *(const short8*)&hs[(mt * 16 + ln) * S1 + ks * 32 + quad * 8];
            #pragma unroll
            for (int mt = 0; mt < 2; ++mt)
                #pragma unroll
                for (int nt = 0; nt < 4; ++nt)
                    acc[mt][nt] = __builtin_amdgcn_mfma_f32_16x16x32_bf16(wcur[nt], b[mt], acc[mt][nt], 0, 0, 0);
            #pragma unroll
            for (int nt = 0; nt < 4; ++nt) wcur[nt] = wnxt[nt];
        }
        __syncthreads();
        #pragma unroll
        for (int mt = 0; mt < 2; ++mt)
            #pragma unroll
            for (int nt = 0; nt < 4; ++nt) {
                const floatx4 v = acc[mt][nt];
                uint2 w;
                w.x = pk(fmaxf(v[0], 0.f), fmaxf(v[1], 0.f));
                w.y = pk(fmaxf(v[2], 0.f), fmaxf(v[3], 0.f));
                *(uint2*)&hs[(mt * 16 + ln) * S1 + nb + nt * 16 + quad * 4] = w;
            }
    }
    __syncthreads();

    // ---- out = r2 @ Wr3 + br3 + bar (N=2, VALU, 8-way K-split) ----
    {
        const int m = t & 31;
        const int p = t >> 5;                     // 8 K-partitions of 32
        float v0 = 0.f, v1 = 0.f;
        #pragma unroll
        for (int kk = 0; kk < 4; ++kk) {
            const int k0 = p * 32 + kk * 8;
            const short8 h = *(const short8*)&hs[m * S1 + k0];
            #pragma unroll
            for (int j = 0; j < 8; ++j) {
                const float hv = bs2f(h[j]);
                v0 = fmaf(hv, Wr3f[(k0 + j) * 2 + 0], v0);
                v1 = fmaf(hv, Wr3f[(k0 + j) * 2 + 1], v1);
            }
        }
        part[p][m][0] = v0;
        part[p][m][1] = v1;
    }
    __syncthreads();
    if (t < 64) {
        const int m = t >> 1, o = t & 1;
        float s = br3f[o] + bar[(long)(a0 + m) * 2 + o];
        #pragma unroll
        for (int p = 0; p < 8; ++p) s += part[p][m][o];
        if (f32) ((float*)out)[(a0 + m) * 2 + o] = s;
        else     ((bf16*)out)[(a0 + m) * 2 + o] = __float2bfloat16(s);
    }
}

extern "C" void kernel_launch(void* const* d_in, const int* in_sizes, int n_in,
                              void* d_out, int out_size, void* d_ws, size_t ws_size,
                              hipStream_t stream)
{
    (void)in_sizes; (void)n_in; (void)out_size;

    const void* ef  = d_in[0];
    const int*  ids = (const int*)d_in[1];

    char* p = (char*)d_ws;
    int*   flag  = (int*)p;        p += 256;
    float* agg   = (float*)p;      p += (size_t)NA * 64 * 4;
    float* bar   = (float*)p;      p += (size_t)NA * 2 * 4;
    short* Wp1P  = (short*)p;      p += 8192 * 2;
    short* Wp2P  = (short*)p;      p += 65536 * 2;
    short* Wp3P  = (short*)p;      p += 32768 * 2;
    short* Wr1T  = (short*)p;      p += 16384 * 2;
    short* Wr2T  = (short*)p;      p += 65536 * 2;
    float* bp1f  = (float*)p;      p += 256 * 4;
    float* bp2f  = (float*)p;      p += 256 * 4;
    float* bp3f  = (float*)p;      p += 64 * 4;
    float* br1f  = (float*)p;      p += 256 * 4;
    float* br2f  = (float*)p;      p += 256 * 4;
    float* Wr3f  = (float*)p;      p += 512 * 4;
    float* br3f  = (float*)p;      p += 256;
    const size_t required = (size_t)(p - (char*)d_ws);
    if (ws_size < required) return;  // signature: output stays zero (absmax ~26)

    hipMemsetAsync(agg, 0, ((size_t)NA * 64 + (size_t)NA * 2) * 4, stream);
    prep_weights_kernel<<<64, 256, 0, stream>>>(
        d_in[2], d_in[3], d_in[4], d_in[5], d_in[6], d_in[7],
        d_in[8], d_in[9], d_in[10], d_in[11], d_in[12], d_in[13],
        Wp1P, Wp2P, Wp3P, Wr1T, Wr2T,
        bp1f, bp2f, bp3f, br1f, br2f, Wr3f, br3f, flag);
    edge_mlp_kernel<<<NE / E, 512, 0, stream>>>(
        ef, ids, Wp1P, bp1f, Wp2P, bp2f, Wp3P, bp3f, agg, bar, flag);
    agent_mlp_kernel<<<NA / AG, 256, 0, stream>>>(
        agg, bar, Wr1T, br1f, Wr2T, br2f, Wr3f, br3f, d_out, flag);
}

// Round 2
// 204.689 us; speedup vs baseline: 1.7378x; 1.0002x over previous
//
#include <hip/hip_runtime.h>
#include <hip/hip_bf16.h>

typedef __hip_bfloat16 bf16;
typedef __attribute__((ext_vector_type(8))) short short8;   // MFMA A/B frag (8 bf16)
typedef __attribute__((ext_vector_type(4))) float floatx4;  // MFMA C/D frag
typedef __attribute__((ext_vector_type(4))) short s16x4;

#define NE 524288
#define NA 16384
#define E  128       // edges per block (edge kernel), 8 waves
#define AG 16        // agents per block (agent kernel), 4 waves, 1024 blocks
#define S1 260       // LDS act row stride (shorts)
#define SH3 68       // h3 overlay row stride (floats)

__device__ __forceinline__ float ld(const void* p, long i, int f32) {
    return f32 ? ((const float*)p)[i] : __bfloat162float(((const bf16*)p)[i]);
}
__device__ __forceinline__ short f2bs(float f) {
    bf16 h = __float2bfloat16(f);
    return *(short*)&h;
}
__device__ __forceinline__ float bs2f(short s) {
    union { unsigned u; float f; } c;
    c.u = ((unsigned)(unsigned short)s) << 16;
    return c.f;
}
// pack 2 floats -> 2 bf16 in one dword (a = low/even n, b = high/odd n)
__device__ __forceinline__ unsigned pk(float a, float b) {
    return ((unsigned)(unsigned short)f2bs(b) << 16) | (unsigned)(unsigned short)f2bs(a);
}

// ---------------------------------------------------------------------------
// Weight prep (dtype detector fused in). ALL MLP weights are packed in exact
// per-(wave,ks,nt,lane) MFMA fragment order so every weight load in both
// compute kernels is ONE fully-coalesced 1 KB global_load_dwordx4:
//   Wp1P[((w*2+nt)*64 + lane)*8 + j]             8 waves x 2 nt, K padded to 32
//   Wp2P[(((w*8+ks)*2+nt)*64 + lane)*8 + j]      8 waves x 8 ks x 2 nt
//   Wp3P[((w*8+ks)*64 + lane)*8 + j]             8 waves (N-split, dup per mh)
//   Wr1P[(((w*2+ks)*4+nt)*64 + lane)*8 + j]      4 waves x 2 ks x 4 nt
//   Wr2P[(((w*8+ks)*4+nt)*64 + lane)*8 + j]      4 waves x 8 ks x 4 nt
// Biases + Wr3 to f32.
// ---------------------------------------------------------------------------
__global__ void prep_weights_kernel(
    const void* __restrict__ Wp1, const void* __restrict__ bp1,
    const void* __restrict__ Wp2, const void* __restrict__ bp2,
    const void* __restrict__ Wp3, const void* __restrict__ bp3,
    const void* __restrict__ Wr1, const void* __restrict__ br1,
    const void* __restrict__ Wr2, const void* __restrict__ br2,
    const void* __restrict__ Wr3, const void* __restrict__ br3,
    short* __restrict__ Wp1P, short* __restrict__ Wp2P, short* __restrict__ Wp3P,
    short* __restrict__ Wr1P,  short* __restrict__ Wr2P,
    float* __restrict__ bp1f, float* __restrict__ bp2f, float* __restrict__ bp3f,
    float* __restrict__ br1f, float* __restrict__ br2f,
    float* __restrict__ Wr3f, float* __restrict__ br3f,
    int* __restrict__ flag)
{
    __shared__ int sflag;
    if (threadIdx.x < 64) {
        const unsigned short* w = (const unsigned short*)Wp2;
        int bad = 0;
        for (int i = threadIdx.x; i < 1024; i += 64) {
            const int e = (w[i] >> 7) & 0xFF;
            if (e >= 131) bad = 1;                // |v|>=16 / inf / nan -> f32 bits
        }
        const unsigned long long m = __ballot(bad);
        if (threadIdx.x == 0) {
            sflag = (m != 0ull) ? 1 : 0;
            if (blockIdx.x == 0) *flag = sflag;
        }
    }
    __syncthreads();
    const int f32 = sflag;

    const int stride = gridDim.x * blockDim.x;
    for (int i = blockIdx.x * blockDim.x + threadIdx.x; i < 190018; i += stride) {
        if (i < 65536) {                       // Wp2P packed frags
            const int j = i & 7, lane = (i >> 3) & 63;
            const int nt = (i >> 9) & 1, ks = (i >> 10) & 7, w = (i >> 13) & 7;
            const int n = w * 32 + nt * 16 + (lane & 15);
            const int k = ks * 32 + (lane >> 4) * 8 + j;
            Wp2P[i] = f2bs(ld(Wp2, (long)k * 256 + n, f32));
        } else if (i < 98304) {                // Wp3P packed frags (N-split, dup per mh)
            const int ii = i - 65536;
            const int j = ii & 7, lane = (ii >> 3) & 63;
            const int ks = (ii >> 9) & 7, w = (ii >> 12) & 7;
            const int n = (w & 3) * 16 + (lane & 15);
            const int k = ks * 32 + (lane >> 4) * 8 + j;
            Wp3P[ii] = f2bs(ld(Wp3, (long)k * 64 + n, f32));
        } else if (i < 106496) {               // Wp1P packed frags, zero-pad k>=4
            const int ii = i - 98304;
            const int j = ii & 7, lane = (ii >> 3) & 63;
            const int nt = (ii >> 9) & 1, w = (ii >> 10) & 7;
            const int n = w * 32 + nt * 16 + (lane & 15);
            const int k = (lane >> 4) * 8 + j;
            Wp1P[ii] = (k < 4) ? f2bs(ld(Wp1, (long)k * 256 + n, f32)) : (short)0;
        } else if (i < 122880) {               // Wr1P packed frags (agent, K=64)
            const int ii = i - 106496;
            const int j = ii & 7, lane = (ii >> 3) & 63;
            const int nt = (ii >> 9) & 3, ks = (ii >> 11) & 1, w = (ii >> 12) & 3;
            const int n = w * 64 + nt * 16 + (lane & 15);
            const int k = ks * 32 + (lane >> 4) * 8 + j;
            Wr1P[ii] = f2bs(ld(Wr1, (long)k * 256 + n, f32));
        } else if (i < 188416) {               // Wr2P packed frags (agent, K=256)
            const int ii = i - 122880;
            const int j = ii & 7, lane = (ii >> 3) & 63;
            const int nt = (ii >> 9) & 3, ks = (ii >> 11) & 7, w = (ii >> 14) & 3;
            const int n = w * 64 + nt * 16 + (lane & 15);
            const int k = ks * 32 + (lane >> 4) * 8 + j;
            Wr2P[ii] = f2bs(ld(Wr2, (long)k * 256 + n, f32));
        } else if (i < 188672) { bp1f[i - 188416] = ld(bp1, i - 188416, f32); }
        else if (i < 188928) { bp2f[i - 188672] = ld(bp2, i - 188672, f32); }
        else if (i < 188992) { bp3f[i - 188928] = ld(bp3, i - 188928, f32); }
        else if (i < 189248) { br1f[i - 188992] = ld(br1, i - 188992, f32); }
        else if (i < 189504) { br2f[i - 189248] = ld(br2, i - 189248, f32); }
        else if (i < 190016) { Wr3f[i - 189504] = ld(Wr3, i - 189504, f32); }
        else                 { br3f[i - 190016] = ld(br3, i - 190016, f32); }
    }
}

// ---------------------------------------------------------------------------
// Edge MLP: 128 edges/block, 8 waves (512 thr). Swapped operands (weights=A,
// activations=B). Waves split N 8-way in layers 1-2; layer 3 splits
// (M-half x N-quarter). XCD-chunked block swizzle; cross-barrier register
// prefetch of next-phase weights/biases; setprio(1) around MFMA clusters.
// ---------------------------------------------------------------------------
__global__ __launch_bounds__(512, 4) void edge_mlp_kernel(
    const void* __restrict__ ef, const int* __restrict__ ids,
    const short* __restrict__ Wp1P, const float* __restrict__ bp1f,
    const short* __restrict__ Wp2P, const float* __restrict__ bp2f,
    const short* __restrict__ Wp3P, const float* __restrict__ bp3f,
    float* __restrict__ agg, float* __restrict__ bar,
    const int* __restrict__ flag)
{
    __shared__ __align__(16) short hs[E * S1];     // 66.6 KB: h1, h2, then h3 overlay
    __shared__ float cb[E][2];
    __shared__ int   sid[E];

    const int t = threadIdx.x;
    const int bid = blockIdx.x;
    // XCD-chunked swizzle: work-adjacent blocks share an XCD (nwg=4096, %8==0)
    const int wg = (bid & 7) * ((NE / E) >> 3) + (bid >> 3);
    const long e0 = (long)wg * E;
    const int f32 = *flag;
    const int wave = t >> 6, lane = t & 63, quad = lane >> 4, ln = lane & 15;
    const int nw = wave * 32;                      // feature base, layers 1-2
    const int me = (wave >> 2) * 64;               // L3 edge base
    const int fb = (wave & 3) * 16;                // L3 feature base

    // ---- hoisted prefetch: L2 ks=0 weight frags + L1/L2 biases.
    // Register loads are NOT drained at barriers -> latency hides under L1.
    short8 wcur[2], wnxt[2];
    #pragma unroll
    for (int nt = 0; nt < 2; ++nt)
        wcur[nt] = *(const short8*)&Wp2P[(((wave * 8 + 0) * 2 + nt) * 64 + lane) * 8];
    float4 b1v[2], b2v[2];
    #pragma unroll
    for (int nt = 0; nt < 2; ++nt) {
        b1v[nt] = *(const float4*)&bp1f[nw + nt * 16 + quad * 4];
        b2v[nt] = *(const float4*)&bp2f[nw + nt * 16 + quad * 4];
    }
    short8 w3;            // L3 first frag, loaded during L2 epilogue
    float4 b3v;

    if (t < E) {
        sid[t] = ids[e0 + t];
        const float px = ld(ef, (e0 + t) * 4 + 0, f32);
        const float py = ld(ef, (e0 + t) * 4 + 1, f32);
        const float d = sqrtf(px * px + py * py);
        const float inv = 1.0f / (d * (d - 0.18f));
        cb[t][0] = -px * inv;
        cb[t][1] = -py * inv;
    }

    // ---- layer 1: h1 = relu(x @ Wp1 + bp1) ----
    {
        short8 b[8];                       // B-frags: edges mt*16+ln (quad 0 holds k<4)
        #pragma unroll
        for (int mt = 0; mt < 8; ++mt) {
            short8 v = {};
            if (quad == 0) {
                const long e = e0 + mt * 16 + ln;
                if (f32) {
                    const float4 x = ((const float4*)ef)[e];
                    v[0] = f2bs(x.x); v[1] = f2bs(x.y); v[2] = f2bs(x.z); v[3] = f2bs(x.w);
                } else {
                    const int2 x = ((const int2*)ef)[e];
                    v[0] = (short)(x.x & 0xffff); v[1] = (short)((unsigned)x.x >> 16);
                    v[2] = (short)(x.y & 0xffff); v[3] = (short)((unsigned)x.y >> 16);
                }
            }
            b[mt] = v;
        }
        floatx4 acc[8][2];                 // [mt][nt], init = bias rows
        #pragma unroll
        for (int nt = 0; nt < 2; ++nt) {
            const floatx4 bi = { b1v[nt].x, b1v[nt].y, b1v[nt].z, b1v[nt].w };
            #pragma unroll
            for (int mt = 0; mt < 8; ++mt) acc[mt][nt] = bi;
        }
        #pragma unroll
        for (int nt = 0; nt < 2; ++nt) {
            const short8 a = *(const short8*)&Wp1P[((wave * 2 + nt) * 64 + lane) * 8];
            #pragma unroll
            for (int mt = 0; mt < 8; ++mt)
                acc[mt][nt] = __builtin_amdgcn_mfma_f32_16x16x32_bf16(a, b[mt], acc[mt][nt], 0, 0, 0);
        }
        #pragma unroll
        for (int mt = 0; mt < 8; ++mt)
            #pragma unroll
            for (int nt = 0; nt < 2; ++nt) {
                const floatx4 v = acc[mt][nt];
                uint2 w;
                w.x = pk(fmaxf(v[0], 0.f), fmaxf(v[1], 0.f));
                w.y = pk(fmaxf(v[2], 0.f), fmaxf(v[3], 0.f));
                *(uint2*)&hs[(mt * 16 + ln) * S1 + nw + nt * 16 + quad * 4] = w;
            }
    }
    __syncthreads();

    // ---- layer 2: h2 = relu(h1 @ Wp2 + bp2); coalesced frags, depth-1 prefetch ----
    {
        floatx4 acc[8][2];
        #pragma unroll
        for (int nt = 0; nt < 2; ++nt) {
            const floatx4 bi = { b2v[nt].x, b2v[nt].y, b2v[nt].z, b2v[nt].w };
            #pragma unroll
            for (int mt = 0; mt < 8; ++mt) acc[mt][nt] = bi;
        }
        #pragma unroll
        for (int ks = 0; ks < 8; ++ks) {
            if (ks < 7) {
                #pragma unroll
                for (int nt = 0; nt < 2; ++nt)
                    wnxt[nt] = *(const short8*)&Wp2P[(((wave * 8 + ks + 1) * 2 + nt) * 64 + lane) * 8];
            }
            #pragma unroll
            for (int mh = 0; mh < 2; ++mh) {       // mt chunks of 4 keep VGPR <= 128
                short8 b[4];
                #pragma unroll
                for (int m4 = 0; m4 < 4; ++m4)
                    b[m4] = *(const short8*)&hs[((mh * 4 + m4) * 16 + ln) * S1 + ks * 32 + quad * 8];
                __builtin_amdgcn_s_setprio(1);
                #pragma unroll
                for (int m4 = 0; m4 < 4; ++m4)
                    #pragma unroll
                    for (int nt = 0; nt < 2; ++nt)
                        acc[mh * 4 + m4][nt] = __builtin_amdgcn_mfma_f32_16x16x32_bf16(wcur[nt], b[m4], acc[mh * 4 + m4][nt], 0, 0, 0);
                __builtin_amdgcn_s_setprio(0);
            }
            #pragma unroll
            for (int nt = 0; nt < 2; ++nt) wcur[nt] = wnxt[nt];
        }
        // prefetch L3 first frag + bias (latency hides under epilogue + barrier)
        w3  = *(const short8*)&Wp3P[((wave * 8 + 0) * 64 + lane) * 8];
        b3v = *(const float4*)&bp3f[fb + quad * 4];
        __syncthreads();   // all h1 reads complete before overwrite
        #pragma unroll
        for (int mt = 0; mt < 8; ++mt)
            #pragma unroll
            for (int nt = 0; nt < 2; ++nt) {
                const floatx4 v = acc[mt][nt];
                uint2 w;
                w.x = pk(fmaxf(v[0], 0.f), fmaxf(v[1], 0.f));
                w.y = pk(fmaxf(v[2], 0.f), fmaxf(v[3], 0.f));
                *(uint2*)&hs[(mt * 16 + ln) * S1 + nw + nt * 16 + quad * 4] = w;
            }
    }
    __syncthreads();

    // ---- layer 3: h3 = h2 @ Wp3 + bp3; wave = (M-half me, N-quarter fb) ----
    floatx4 acc3[4];
    {
        const floatx4 bi = { b3v.x, b3v.y, b3v.z, b3v.w };
        #pragma unroll
        for (int mt = 0; mt < 4; ++mt) acc3[mt] = bi;
        #pragma unroll
        for (int ks = 0; ks < 8; ++ks) {
            short8 wn = w3;
            if (ks < 7)
                wn = *(const short8*)&Wp3P[((wave * 8 + ks + 1) * 64 + lane) * 8];
            short8 b[4];
            #pragma unroll
            for (int mt = 0; mt < 4; ++mt)
                b[mt] = *(const short8*)&hs[(me + mt * 16 + ln) * S1 + ks * 32 + quad * 8];
            __builtin_amdgcn_s_setprio(1);
            #pragma unroll
            for (int mt = 0; mt < 4; ++mt)
                acc3[mt] = __builtin_amdgcn_mfma_f32_16x16x32_bf16(w3, b[mt], acc3[mt], 0, 0, 0);
            __builtin_amdgcn_s_setprio(0);
            w3 = wn;
        }
    }
    __syncthreads();       // every wave finished reading h2 before overlay write
    float* h3f = (float*)hs;                       // f32 overlay [128][SH3]
    #pragma unroll
    for (int mt = 0; mt < 4; ++mt) {
        float4 v = { acc3[mt][0], acc3[mt][1], acc3[mt][2], acc3[mt][3] };
        *(float4*)&h3f[(me + mt * 16 + ln) * SH3 + fb + quad * 4] = v;
    }
    __syncthreads();

    // ---- scatter: each wave handles its own 16-edge window (ids sorted) ----
    {
        const int w0 = wave * 16;
        const int f = lane;                     // feature 0..63
        int cur = sid[w0];
        float local = h3f[w0 * SH3 + f];
        #pragma unroll
        for (int e = 1; e < 16; ++e) {
            const int id = sid[w0 + e];
            const float v = h3f[(w0 + e) * SH3 + f];
            if (id == cur) local += v;
            else { atomicAdd(&agg[(long)cur * 64 + f], local); cur = id; local = v; }
        }
        atomicAdd(&agg[(long)cur * 64 + f], local);

        if (lane < 2) {
            int c2 = sid[w0];
            float l2 = cb[w0][lane];
            #pragma unroll
            for (int e = 1; e < 16; ++e) {
                const int id = sid[w0 + e];
                const float v = cb[w0 + e][lane];
                if (id == c2) l2 += v;
                else { atomicAdd(&bar[c2 * 2 + lane], l2); c2 = id; l2 = v; }
            }
            atomicAdd(&bar[c2 * 2 + lane], l2);
        }
    }
}

// ---------------------------------------------------------------------------
// Agent MLP: 16 agents/block, 4 waves (N-split 4x64), 1024 blocks -> 4
// blocks/CU (16 waves/CU). All weight loads coalesced 1 KB packed frags.
// ---------------------------------------------------------------------------
__global__ __launch_bounds__(256, 4) void agent_mlp_kernel(
    const float* __restrict__ agg, const float* __restrict__ bar,
    const short* __restrict__ Wr1P, const float* __restrict__ br1f,
    const short* __restrict__ Wr2P, const float* __restrict__ br2f,
    const float* __restrict__ Wr3f, const float* __restrict__ br3f,
    void* __restrict__ out, const int* __restrict__ flag)
{
    __shared__ __align__(16) short ha[AG * 68];    // bf16 agg (2.2 KB)
    __shared__ __align__(16) short hs[AG * S1];    // r1, then r2 (8.3 KB)
    __shared__ float part[16][AG][2];              // 2 KB

    const int t = threadIdx.x;
    const int a0 = blockIdx.x * AG;
    const int f32 = *flag;
    const int wave = t >> 6, lane = t & 63, quad = lane >> 4, ln = lane & 15;
    const int nb = wave * 64;

    // ---- hoisted prefetch: biases, r1 ks=0 frags, r2 ks=0 frags, bar ----
    float4 r1b[4], r2b[4];
    #pragma unroll
    for (int nt = 0; nt < 4; ++nt) {
        r1b[nt] = *(const float4*)&br1f[nb + nt * 16 + quad * 4];
        r2b[nt] = *(const float4*)&br2f[nb + nt * 16 + quad * 4];
    }
    short8 a1[4], wcur[4], wnxt[4];
    #pragma unroll
    for (int nt = 0; nt < 4; ++nt) {
        a1[nt]   = *(const short8*)&Wr1P[(((wave * 2 + 0) * 4 + nt) * 64 + lane) * 8];
        wcur[nt] = *(const short8*)&Wr2P[(((wave * 8 + 0) * 4 + nt) * 64 + lane) * 8];
    }
    float barv = 0.f;
    if (t < 2 * AG) barv = bar[(long)a0 * 2 + t];

    // ---- stage agg as bf16 (16 agents x 64 feats, 1 float4/thread) ----
    {
        const float4 x = ((const float4*)agg)[(long)blockIdx.x * 256 + t];
        s16x4 v = { f2bs(x.x), f2bs(x.y), f2bs(x.z), f2bs(x.w) };
        *(s16x4*)&ha[(t >> 4) * 68 + (t & 15) * 4] = v;
    }
    __syncthreads();

    // ---- r1 = relu(a @ Wr1 + br1), K=64, M=16 ----
    {
        floatx4 acc[4];
        #pragma unroll
        for (int nt = 0; nt < 4; ++nt)
            acc[nt] = (floatx4){ r1b[nt].x, r1b[nt].y, r1b[nt].z, r1b[nt].w };
        #pragma unroll
        for (int ks = 0; ks < 2; ++ks) {
            const short8 b = *(const short8*)&ha[ln * 68 + ks * 32 + quad * 8];
            short8 a[4];
            #pragma unroll
            for (int nt = 0; nt < 4; ++nt)
                a[nt] = (ks == 0) ? a1[nt]
                      : *(const short8*)&Wr1P[(((wave * 2 + ks) * 4 + nt) * 64 + lane) * 8];
            __builtin_amdgcn_s_setprio(1);
            #pragma unroll
            for (int nt = 0; nt < 4; ++nt)
                acc[nt] = __builtin_amdgcn_mfma_f32_16x16x32_bf16(a[nt], b, acc[nt], 0, 0, 0);
            __builtin_amdgcn_s_setprio(0);
        }
        #pragma unroll
        for (int nt = 0; nt < 4; ++nt) {
            const floatx4 v = acc[nt];
            uint2 w;
            w.x = pk(fmaxf(v[0], 0.f), fmaxf(v[1], 0.f));
            w.y = pk(fmaxf(v[2], 0.f), fmaxf(v[3], 0.f));
            *(uint2*)&hs[ln * S1 + nb + nt * 16 + quad * 4] = w;
        }
    }
    __syncthreads();

    // ---- r2 = relu(r1 @ Wr2 + br2), K=256, depth-1 prefetch ----
    {
        floatx4 acc[4];
        #pragma unroll
        for (int nt = 0; nt < 4; ++nt)
            acc[nt] = (floatx4){ r2b[nt].x, r2b[nt].y, r2b[nt].z, r2b[nt].w };
        #pragma unroll
        for (int ks = 0; ks < 8; ++ks) {
            if (ks < 7) {
                #pragma unroll
                for (int nt = 0; nt < 4; ++nt)
                    wnxt[nt] = *(const short8*)&Wr2P[(((wave * 8 + ks + 1) * 4 + nt) * 64 + lane) * 8];
            }
            const short8 b = *(const short8*)&hs[ln * S1 + ks * 32 + quad * 8];
            __builtin_amdgcn_s_setprio(1);
            #pragma unroll
            for (int nt = 0; nt < 4; ++nt)
                acc[nt] = __builtin_amdgcn_mfma_f32_16x16x32_bf16(wcur[nt], b, acc[nt], 0, 0, 0);
            __builtin_amdgcn_s_setprio(0);
            #pragma unroll
            for (int nt = 0; nt < 4; ++nt) wcur[nt] = wnxt[nt];
        }
        __syncthreads();
        #pragma unroll
        for (int nt = 0; nt < 4; ++nt) {
            const floatx4 v = acc[nt];
            uint2 w;
            w.x = pk(fmaxf(v[0], 0.f), fmaxf(v[1], 0.f));
            w.y = pk(fmaxf(v[2], 0.f), fmaxf(v[3], 0.f));
            *(uint2*)&hs[ln * S1 + nb + nt * 16 + quad * 4] = w;
        }
    }
    __syncthreads();

    // ---- out = r2 @ Wr3 + br3 + bar (N=2, VALU, 16-way K-split) ----
    {
        const int m = t & 15;
        const int p = t >> 4;                     // 16 K-partitions of 16
        float v0 = 0.f, v1 = 0.f;
        #pragma unroll
        for (int kk = 0; kk < 2; ++kk) {
            const int k0 = p * 16 + kk * 8;
            const short8 h = *(const short8*)&hs[m * S1 + k0];
            #pragma unroll
            for (int j = 0; j < 8; ++j) {
                const float hv = bs2f(h[j]);
                v0 = fmaf(hv, Wr3f[(k0 + j) * 2 + 0], v0);
                v1 = fmaf(hv, Wr3f[(k0 + j) * 2 + 1], v1);
            }
        }
        part[p][m][0] = v0;
        part[p][m][1] = v1;
    }
    __syncthreads();
    if (t < 2 * AG) {
        const int m = t >> 1, o = t & 1;
        float s = br3f[o] + barv;
        #pragma unroll
        for (int p = 0; p < 16; ++p) s += part[p][m][o];
        if (f32) ((float*)out)[a0 * 2 + t] = s;
        else     ((bf16*)out)[a0 * 2 + t] = __float2bfloat16(s);
    }
}

extern "C" void kernel_launch(void* const* d_in, const int* in_sizes, int n_in,
                              void* d_out, int out_size, void* d_ws, size_t ws_size,
                              hipStream_t stream)
{
    (void)in_sizes; (void)n_in; (void)out_size;

    const void* ef  = d_in[0];
    const int*  ids = (const int*)d_in[1];

    char* p = (char*)d_ws;
    int*   flag  = (int*)p;        p += 256;
    float* agg   = (float*)p;      p += (size_t)NA * 64 * 4;
    float* bar   = (float*)p;      p += (size_t)NA * 2 * 4;
    short* Wp1P  = (short*)p;      p += 8192 * 2;
    short* Wp2P  = (short*)p;      p += 65536 * 2;
    short* Wp3P  = (short*)p;      p += 32768 * 2;
    short* Wr1P  = (short*)p;      p += 16384 * 2;
    short* Wr2P  = (short*)p;      p += 65536 * 2;
    float* bp1f  = (float*)p;      p += 256 * 4;
    float* bp2f  = (float*)p;      p += 256 * 4;
    float* bp3f  = (float*)p;      p += 64 * 4;
    float* br1f  = (float*)p;      p += 256 * 4;
    float* br2f  = (float*)p;      p += 256 * 4;
    float* Wr3f  = (float*)p;      p += 512 * 4;
    float* br3f  = (float*)p;      p += 256;
    const size_t required = (size_t)(p - (char*)d_ws);
    if (ws_size < required) return;  // signature: output stays zero (absmax ~26)

    hipMemsetAsync(agg, 0, ((size_t)NA * 64 + (size_t)NA * 2) * 4, stream);
    prep_weights_kernel<<<64, 256, 0, stream>>>(
        d_in[2], d_in[3], d_in[4], d_in[5], d_in[6], d_in[7],
        d_in[8], d_in[9], d_in[10], d_in[11], d_in[12], d_in[13],
        Wp1P, Wp2P, Wp3P, Wr1P, Wr2P,
        bp1f, bp2f, bp3f, br1f, br2f, Wr3f, br3f, flag);
    edge_mlp_kernel<<<NE / E, 512, 0, stream>>>(
        ef, ids, Wp1P, bp1f, Wp2P, bp2f, Wp3P, bp3f, agg, bar, flag);
    agent_mlp_kernel<<<NA / AG, 256, 0, stream>>>(
        agg, bar, Wr1P, br1f, Wr2P, br2f, Wr3f, br3f, d_out, flag);
}

// Round 3
// 189.579 us; speedup vs baseline: 1.8763x; 1.0797x over previous
//
#include <hip/hip_runtime.h>
#include <hip/hip_bf16.h>

typedef __hip_bfloat16 bf16;
typedef __attribute__((ext_vector_type(8))) short short8;   // MFMA A/B frag (8 bf16)
typedef __attribute__((ext_vector_type(4))) float floatx4;  // MFMA C/D frag

#define NE 524288
#define NA 16384
#define E  128       // edges per block (edge kernel), 8 waves
#define AG 16        // agents per block (agent kernel), 4 waves, 1024 blocks
#define S1 260       // LDS act row stride (shorts)
#define SH3 68       // h3 overlay row stride (floats)

__device__ __forceinline__ float ld(const void* p, long i, int f32) {
    return f32 ? ((const float*)p)[i] : __bfloat162float(((const bf16*)p)[i]);
}
__device__ __forceinline__ short f2bs(float f) {
    bf16 h = __float2bfloat16(f);
    return *(short*)&h;
}
__device__ __forceinline__ float bs2f(short s) {
    union { unsigned u; float f; } c;
    c.u = ((unsigned)(unsigned short)s) << 16;
    return c.f;
}
// pack 2 floats -> 2 bf16 in one dword (a = low, b = high), single HW instr.
// gfx950 has v_cvt_pk_bf16_f32 but no builtin (learn_hip m240) -> inline asm.
__device__ __forceinline__ unsigned pk(float a, float b) {
    unsigned r;
    asm("v_cvt_pk_bf16_f32 %0, %1, %2" : "=v"(r) : "v"(a), "v"(b));
    return r;
}

// ---------------------------------------------------------------------------
// Weight prep (dtype detector fused in) + agg/bar zero-fill (replaces the
// separate hipMemsetAsync dispatch). 512 blocks for TLP on the scattered
// transpose reads. ALL MLP weights packed in exact per-(wave,ks,nt,lane)
// MFMA fragment order so every weight load in both compute kernels is ONE
// fully-coalesced 1 KB global_load_dwordx4:
//   Wp1P[((w*2+nt)*64 + lane)*8 + j]             8 waves x 2 nt, K padded to 32
//   Wp2P[(((w*8+ks)*2+nt)*64 + lane)*8 + j]      8 waves x 8 ks x 2 nt
//   Wp3P[((w*8+ks)*64 + lane)*8 + j]             8 waves (N-split, dup per mh)
//   Wr1P[(((w*2+ks)*4+nt)*64 + lane)*8 + j]      4 waves x 2 ks x 4 nt
//   Wr2P[(((w*8+ks)*4+nt)*64 + lane)*8 + j]      4 waves x 8 ks x 4 nt
// Biases + Wr3 to f32.
// ---------------------------------------------------------------------------
__global__ void prep_weights_kernel(
    const void* __restrict__ Wp1, const void* __restrict__ bp1,
    const void* __restrict__ Wp2, const void* __restrict__ bp2,
    const void* __restrict__ Wp3, const void* __restrict__ bp3,
    const void* __restrict__ Wr1, const void* __restrict__ br1,
    const void* __restrict__ Wr2, const void* __restrict__ br2,
    const void* __restrict__ Wr3, const void* __restrict__ br3,
    short* __restrict__ Wp1P, short* __restrict__ Wp2P, short* __restrict__ Wp3P,
    short* __restrict__ Wr1P,  short* __restrict__ Wr2P,
    float* __restrict__ bp1f, float* __restrict__ bp2f, float* __restrict__ bp3f,
    float* __restrict__ br1f, float* __restrict__ br2f,
    float* __restrict__ Wr3f, float* __restrict__ br3f,
    float* __restrict__ agg,   // agg (NA*64) + bar (NA*2), contiguous
    int* __restrict__ flag)
{
    const int tid = blockIdx.x * blockDim.x + threadIdx.x;
    const int stride = gridDim.x * blockDim.x;

    // zero agg+bar (contiguous, float4-aligned): NA*66/4 = 270336 vec4 stores
    {
        const float4 z = { 0.f, 0.f, 0.f, 0.f };
        float4* dst = (float4*)agg;
        for (int i = tid; i < (NA * 66) / 4; i += stride) dst[i] = z;
    }

    __shared__ int sflag;
    if (threadIdx.x < 64) {
        const unsigned short* w = (const unsigned short*)Wp2;
        int bad = 0;
        for (int i = threadIdx.x; i < 1024; i += 64) {
            const int e = (w[i] >> 7) & 0xFF;
            if (e >= 131) bad = 1;                // |v|>=16 / inf / nan -> f32 bits
        }
        const unsigned long long m = __ballot(bad);
        if (threadIdx.x == 0) {
            sflag = (m != 0ull) ? 1 : 0;
            if (blockIdx.x == 0) *flag = sflag;
        }
    }
    __syncthreads();
    const int f32 = sflag;

    for (int i = tid; i < 190018; i += stride) {
        if (i < 65536) {                       // Wp2P packed frags
            const int j = i & 7, lane = (i >> 3) & 63;
            const int nt = (i >> 9) & 1, ks = (i >> 10) & 7, w = (i >> 13) & 7;
            const int n = w * 32 + nt * 16 + (lane & 15);
            const int k = ks * 32 + (lane >> 4) * 8 + j;
            Wp2P[i] = f2bs(ld(Wp2, (long)k * 256 + n, f32));
        } else if (i < 98304) {                // Wp3P packed frags (N-split, dup per mh)
            const int ii = i - 65536;
            const int j = ii & 7, lane = (ii >> 3) & 63;
            const int ks = (ii >> 9) & 7, w = (ii >> 12) & 7;
            const int n = (w & 3) * 16 + (lane & 15);
            const int k = ks * 32 + (lane >> 4) * 8 + j;
            Wp3P[ii] = f2bs(ld(Wp3, (long)k * 64 + n, f32));
        } else if (i < 106496) {               // Wp1P packed frags, zero-pad k>=4
            const int ii = i - 98304;
            const int j = ii & 7, lane = (ii >> 3) & 63;
            const int nt = (ii >> 9) & 1, w = (ii >> 10) & 7;
            const int n = w * 32 + nt * 16 + (lane & 15);
            const int k = (lane >> 4) * 8 + j;
            Wp1P[ii] = (k < 4) ? f2bs(ld(Wp1, (long)k * 256 + n, f32)) : (short)0;
        } else if (i < 122880) {               // Wr1P packed frags (agent, K=64)
            const int ii = i - 106496;
            const int j = ii & 7, lane = (ii >> 3) & 63;
            const int nt = (ii >> 9) & 3, ks = (ii >> 11) & 1, w = (ii >> 12) & 3;
            const int n = w * 64 + nt * 16 + (lane & 15);
            const int k = ks * 32 + (lane >> 4) * 8 + j;
            Wr1P[ii] = f2bs(ld(Wr1, (long)k * 256 + n, f32));
        } else if (i < 188416) {               // Wr2P packed frags (agent, K=256)
            const int ii = i - 122880;
            const int j = ii & 7, lane = (ii >> 3) & 63;
            const int nt = (ii >> 9) & 3, ks = (ii >> 11) & 7, w = (ii >> 14) & 3;
            const int n = w * 64 + nt * 16 + (lane & 15);
            const int k = ks * 32 + (lane >> 4) * 8 + j;
            Wr2P[ii] = f2bs(ld(Wr2, (long)k * 256 + n, f32));
        } else if (i < 188672) { bp1f[i - 188416] = ld(bp1, i - 188416, f32); }
        else if (i < 188928) { bp2f[i - 188672] = ld(bp2, i - 188672, f32); }
        else if (i < 188992) { bp3f[i - 188928] = ld(bp3, i - 188928, f32); }
        else if (i < 189248) { br1f[i - 188992] = ld(br1, i - 188992, f32); }
        else if (i < 189504) { br2f[i - 189248] = ld(br2, i - 189248, f32); }
        else if (i < 190016) { Wr3f[i - 189504] = ld(Wr3, i - 189504, f32); }
        else                 { br3f[i - 190016] = ld(br3, i - 190016, f32); }
    }
}

// ---------------------------------------------------------------------------
// Edge MLP: 128 edges/block, 8 waves (512 thr). Swapped operands (weights=A,
// activations=B). Waves split N 8-way in layers 1-2; layer 3 splits
// (M-half x N-quarter). XCD-chunked block swizzle; cross-barrier register
// prefetch of next-phase weights/biases; setprio(1) around MFMA clusters;
// single-instruction v_cvt_pk_bf16_f32 epilogues.
// ---------------------------------------------------------------------------
__global__ __launch_bounds__(512, 4) void edge_mlp_kernel(
    const void* __restrict__ ef, const int* __restrict__ ids,
    const short* __restrict__ Wp1P, const float* __restrict__ bp1f,
    const short* __restrict__ Wp2P, const float* __restrict__ bp2f,
    const short* __restrict__ Wp3P, const float* __restrict__ bp3f,
    float* __restrict__ agg, float* __restrict__ bar,
    const int* __restrict__ flag)
{
    __shared__ __align__(16) short hs[E * S1];     // 66.6 KB: h1, h2, then h3 overlay
    __shared__ float cb[E][2];
    __shared__ int   sid[E];

    const int t = threadIdx.x;
    const int bid = blockIdx.x;
    // XCD-chunked swizzle: work-adjacent blocks share an XCD (nwg=4096, %8==0)
    const int wg = (bid & 7) * ((NE / E) >> 3) + (bid >> 3);
    const long e0 = (long)wg * E;
    const int f32 = *flag;
    const int wave = t >> 6, lane = t & 63, quad = lane >> 4, ln = lane & 15;
    const int nw = wave * 32;                      // feature base, layers 1-2
    const int me = (wave >> 2) * 64;               // L3 edge base
    const int fb = (wave & 3) * 16;                // L3 feature base

    // ---- hoisted prefetch: L2 ks=0 weight frags + L1/L2 biases.
    // Register loads are NOT drained at barriers -> latency hides under L1.
    short8 wcur[2], wnxt[2];
    #pragma unroll
    for (int nt = 0; nt < 2; ++nt)
        wcur[nt] = *(const short8*)&Wp2P[(((wave * 8 + 0) * 2 + nt) * 64 + lane) * 8];
    float4 b1v[2], b2v[2];
    #pragma unroll
    for (int nt = 0; nt < 2; ++nt) {
        b1v[nt] = *(const float4*)&bp1f[nw + nt * 16 + quad * 4];
        b2v[nt] = *(const float4*)&bp2f[nw + nt * 16 + quad * 4];
    }
    short8 w3;            // L3 first frag, loaded during L2 epilogue
    float4 b3v;

    if (t < E) {
        sid[t] = ids[e0 + t];
        const float px = ld(ef, (e0 + t) * 4 + 0, f32);
        const float py = ld(ef, (e0 + t) * 4 + 1, f32);
        const float d = sqrtf(px * px + py * py);
        const float inv = 1.0f / (d * (d - 0.18f));
        cb[t][0] = -px * inv;
        cb[t][1] = -py * inv;
    }

    // ---- layer 1: h1 = relu(x @ Wp1 + bp1) ----
    {
        short8 b[8];                       // B-frags: edges mt*16+ln (quad 0 holds k<4)
        #pragma unroll
        for (int mt = 0; mt < 8; ++mt) {
            short8 v = {};
            if (quad == 0) {
                const long e = e0 + mt * 16 + ln;
                if (f32) {
                    const float4 x = ((const float4*)ef)[e];
                    v[0] = f2bs(x.x); v[1] = f2bs(x.y); v[2] = f2bs(x.z); v[3] = f2bs(x.w);
                } else {
                    const int2 x = ((const int2*)ef)[e];
                    v[0] = (short)(x.x & 0xffff); v[1] = (short)((unsigned)x.x >> 16);
                    v[2] = (short)(x.y & 0xffff); v[3] = (short)((unsigned)x.y >> 16);
                }
            }
            b[mt] = v;
        }
        floatx4 acc[8][2];                 // [mt][nt], init = bias rows
        #pragma unroll
        for (int nt = 0; nt < 2; ++nt) {
            const floatx4 bi = { b1v[nt].x, b1v[nt].y, b1v[nt].z, b1v[nt].w };
            #pragma unroll
            for (int mt = 0; mt < 8; ++mt) acc[mt][nt] = bi;
        }
        #pragma unroll
        for (int nt = 0; nt < 2; ++nt) {
            const short8 a = *(const short8*)&Wp1P[((wave * 2 + nt) * 64 + lane) * 8];
            #pragma unroll
            for (int mt = 0; mt < 8; ++mt)
                acc[mt][nt] = __builtin_amdgcn_mfma_f32_16x16x32_bf16(a, b[mt], acc[mt][nt], 0, 0, 0);
        }
        #pragma unroll
        for (int mt = 0; mt < 8; ++mt)
            #pragma unroll
            for (int nt = 0; nt < 2; ++nt) {
                const floatx4 v = acc[mt][nt];
                uint2 w;
                w.x = pk(fmaxf(v[0], 0.f), fmaxf(v[1], 0.f));
                w.y = pk(fmaxf(v[2], 0.f), fmaxf(v[3], 0.f));
                *(uint2*)&hs[(mt * 16 + ln) * S1 + nw + nt * 16 + quad * 4] = w;
            }
    }
    __syncthreads();

    // ---- layer 2: h2 = relu(h1 @ Wp2 + bp2); coalesced frags, depth-1 prefetch ----
    {
        floatx4 acc[8][2];
        #pragma unroll
        for (int nt = 0; nt < 2; ++nt) {
            const floatx4 bi = { b2v[nt].x, b2v[nt].y, b2v[nt].z, b2v[nt].w };
            #pragma unroll
            for (int mt = 0; mt < 8; ++mt) acc[mt][nt] = bi;
        }
        #pragma unroll
        for (int ks = 0; ks < 8; ++ks) {
            if (ks < 7) {
                #pragma unroll
                for (int nt = 0; nt < 2; ++nt)
                    wnxt[nt] = *(const short8*)&Wp2P[(((wave * 8 + ks + 1) * 2 + nt) * 64 + lane) * 8];
            }
            #pragma unroll
            for (int mh = 0; mh < 2; ++mh) {       // mt chunks of 4 keep VGPR low
                short8 b[4];
                #pragma unroll
                for (int m4 = 0; m4 < 4; ++m4)
                    b[m4] = *(const short8*)&hs[((mh * 4 + m4) * 16 + ln) * S1 + ks * 32 + quad * 8];
                __builtin_amdgcn_s_setprio(1);
                #pragma unroll
                for (int m4 = 0; m4 < 4; ++m4)
                    #pragma unroll
                    for (int nt = 0; nt < 2; ++nt)
                        acc[mh * 4 + m4][nt] = __builtin_amdgcn_mfma_f32_16x16x32_bf16(wcur[nt], b[m4], acc[mh * 4 + m4][nt], 0, 0, 0);
                __builtin_amdgcn_s_setprio(0);
            }
            #pragma unroll
            for (int nt = 0; nt < 2; ++nt) wcur[nt] = wnxt[nt];
        }
        // prefetch L3 first frag + bias (latency hides under epilogue + barrier)
        w3  = *(const short8*)&Wp3P[((wave * 8 + 0) * 64 + lane) * 8];
        b3v = *(const float4*)&bp3f[fb + quad * 4];
        __syncthreads();   // all h1 reads complete before overwrite
        #pragma unroll
        for (int mt = 0; mt < 8; ++mt)
            #pragma unroll
            for (int nt = 0; nt < 2; ++nt) {
                const floatx4 v = acc[mt][nt];
                uint2 w;
                w.x = pk(fmaxf(v[0], 0.f), fmaxf(v[1], 0.f));
                w.y = pk(fmaxf(v[2], 0.f), fmaxf(v[3], 0.f));
                *(uint2*)&hs[(mt * 16 + ln) * S1 + nw + nt * 16 + quad * 4] = w;
            }
    }
    __syncthreads();

    // ---- layer 3: h3 = h2 @ Wp3 + bp3; wave = (M-half me, N-quarter fb) ----
    floatx4 acc3[4];
    {
        const floatx4 bi = { b3v.x, b3v.y, b3v.z, b3v.w };
        #pragma unroll
        for (int mt = 0; mt < 4; ++mt) acc3[mt] = bi;
        #pragma unroll
        for (int ks = 0; ks < 8; ++ks) {
            short8 wn = w3;
            if (ks < 7)
                wn = *(const short8*)&Wp3P[((wave * 8 + ks + 1) * 64 + lane) * 8];
            short8 b[4];
            #pragma unroll
            for (int mt = 0; mt < 4; ++mt)
                b[mt] = *(const short8*)&hs[(me + mt * 16 + ln) * S1 + ks * 32 + quad * 8];
            __builtin_amdgcn_s_setprio(1);
            #pragma unroll
            for (int mt = 0; mt < 4; ++mt)
                acc3[mt] = __builtin_amdgcn_mfma_f32_16x16x32_bf16(w3, b[mt], acc3[mt], 0, 0, 0);
            __builtin_amdgcn_s_setprio(0);
            w3 = wn;
        }
    }
    __syncthreads();       // every wave finished reading h2 before overlay write
    float* h3f = (float*)hs;                       // f32 overlay [128][SH3]
    #pragma unroll
    for (int mt = 0; mt < 4; ++mt) {
        float4 v = { acc3[mt][0], acc3[mt][1], acc3[mt][2], acc3[mt][3] };
        *(float4*)&h3f[(me + mt * 16 + ln) * SH3 + fb + quad * 4] = v;
    }
    __syncthreads();

    // ---- scatter: each wave handles its own 16-edge window (ids sorted) ----
    {
        const int w0 = wave * 16;
        const int f = lane;                     // feature 0..63
        int cur = sid[w0];
        float local = h3f[w0 * SH3 + f];
        #pragma unroll
        for (int e = 1; e < 16; ++e) {
            const int id = sid[w0 + e];
            const float v = h3f[(w0 + e) * SH3 + f];
            if (id == cur) local += v;
            else { atomicAdd(&agg[(long)cur * 64 + f], local); cur = id; local = v; }
        }
        atomicAdd(&agg[(long)cur * 64 + f], local);

        if (lane < 2) {
            int c2 = sid[w0];
            float l2 = cb[w0][lane];
            #pragma unroll
            for (int e = 1; e < 16; ++e) {
                const int id = sid[w0 + e];
                const float v = cb[w0 + e][lane];
                if (id == c2) l2 += v;
                else { atomicAdd(&bar[c2 * 2 + lane], l2); c2 = id; l2 = v; }
            }
            atomicAdd(&bar[c2 * 2 + lane], l2);
        }
    }
}

// ---------------------------------------------------------------------------
// Agent MLP: 16 agents/block, 4 waves (N-split 4x64), 1024 blocks -> 4
// blocks/CU (16 waves/CU). All weight loads coalesced 1 KB packed frags.
// ---------------------------------------------------------------------------
__global__ __launch_bounds__(256, 4) void agent_mlp_kernel(
    const float* __restrict__ agg, const float* __restrict__ bar,
    const short* __restrict__ Wr1P, const float* __restrict__ br1f,
    const short* __restrict__ Wr2P, const float* __restrict__ br2f,
    const float* __restrict__ Wr3f, const float* __restrict__ br3f,
    void* __restrict__ out, const int* __restrict__ flag)
{
    __shared__ __align__(16) short ha[AG * 68];    // bf16 agg (2.2 KB)
    __shared__ __align__(16) short hs[AG * S1];    // r1, then r2 (8.3 KB)
    __shared__ float part[16][AG][2];              // 2 KB

    const int t = threadIdx.x;
    const int a0 = blockIdx.x * AG;
    const int f32 = *flag;
    const int wave = t >> 6, lane = t & 63, quad = lane >> 4, ln = lane & 15;
    const int nb = wave * 64;

    // ---- hoisted prefetch: biases, r1 ks=0 frags, r2 ks=0 frags, bar ----
    float4 r1b[4], r2b[4];
    #pragma unroll
    for (int nt = 0; nt < 4; ++nt) {
        r1b[nt] = *(const float4*)&br1f[nb + nt * 16 + quad * 4];
        r2b[nt] = *(const float4*)&br2f[nb + nt * 16 + quad * 4];
    }
    short8 a1[4], wcur[4], wnxt[4];
    #pragma unroll
    for (int nt = 0; nt < 4; ++nt) {
        a1[nt]   = *(const short8*)&Wr1P[(((wave * 2 + 0) * 4 + nt) * 64 + lane) * 8];
        wcur[nt] = *(const short8*)&Wr2P[(((wave * 8 + 0) * 4 + nt) * 64 + lane) * 8];
    }
    float barv = 0.f;
    if (t < 2 * AG) barv = bar[(long)a0 * 2 + t];

    // ---- stage agg as bf16 (16 agents x 64 feats, 1 float4/thread) ----
    {
        const float4 x = ((const float4*)agg)[(long)blockIdx.x * 256 + t];
        uint2 w;
        w.x = pk(x.x, x.y);
        w.y = pk(x.z, x.w);
        *(uint2*)&ha[(t >> 4) * 68 + (t & 15) * 4] = w;
    }
    __syncthreads();

    // ---- r1 = relu(a @ Wr1 + br1), K=64, M=16 ----
    {
        floatx4 acc[4];
        #pragma unroll
        for (int nt = 0; nt < 4; ++nt)
            acc[nt] = (floatx4){ r1b[nt].x, r1b[nt].y, r1b[nt].z, r1b[nt].w };
        #pragma unroll
        for (int ks = 0; ks < 2; ++ks) {
            const short8 b = *(const short8*)&ha[ln * 68 + ks * 32 + quad * 8];
            short8 a[4];
            #pragma unroll
            for (int nt = 0; nt < 4; ++nt)
                a[nt] = (ks == 0) ? a1[nt]
                      : *(const short8*)&Wr1P[(((wave * 2 + ks) * 4 + nt) * 64 + lane) * 8];
            __builtin_amdgcn_s_setprio(1);
            #pragma unroll
            for (int nt = 0; nt < 4; ++nt)
                acc[nt] = __builtin_amdgcn_mfma_f32_16x16x32_bf16(a[nt], b, acc[nt], 0, 0, 0);
            __builtin_amdgcn_s_setprio(0);
        }
        #pragma unroll
        for (int nt = 0; nt < 4; ++nt) {
            const floatx4 v = acc[nt];
            uint2 w;
            w.x = pk(fmaxf(v[0], 0.f), fmaxf(v[1], 0.f));
            w.y = pk(fmaxf(v[2], 0.f), fmaxf(v[3], 0.f));
            *(uint2*)&hs[ln * S1 + nb + nt * 16 + quad * 4] = w;
        }
    }
    __syncthreads();

    // ---- r2 = relu(r1 @ Wr2 + br2), K=256, depth-1 prefetch ----
    {
        floatx4 acc[4];
        #pragma unroll
        for (int nt = 0; nt < 4; ++nt)
            acc[nt] = (floatx4){ r2b[nt].x, r2b[nt].y, r2b[nt].z, r2b[nt].w };
        #pragma unroll
        for (int ks = 0; ks < 8; ++ks) {
            if (ks < 7) {
                #pragma unroll
                for (int nt = 0; nt < 4; ++nt)
                    wnxt[nt] = *(const short8*)&Wr2P[(((wave * 8 + ks + 1) * 4 + nt) * 64 + lane) * 8];
            }
            const short8 b = *(const short8*)&hs[ln * S1 + ks * 32 + quad * 8];
            __builtin_amdgcn_s_setprio(1);
            #pragma unroll
            for (int nt = 0; nt < 4; ++nt)
                acc[nt] = __builtin_amdgcn_mfma_f32_16x16x32_bf16(wcur[nt], b, acc[nt], 0, 0, 0);
            __builtin_amdgcn_s_setprio(0);
            #pragma unroll
            for (int nt = 0; nt < 4; ++nt) wcur[nt] = wnxt[nt];
        }
        __syncthreads();
        #pragma unroll
        for (int nt = 0; nt < 4; ++nt) {
            const floatx4 v = acc[nt];
            uint2 w;
            w.x = pk(fmaxf(v[0], 0.f), fmaxf(v[1], 0.f));
            w.y = pk(fmaxf(v[2], 0.f), fmaxf(v[3], 0.f));
            *(uint2*)&hs[ln * S1 + nb + nt * 16 + quad * 4] = w;
        }
    }
    __syncthreads();

    // ---- out = r2 @ Wr3 + br3 + bar (N=2, VALU, 16-way K-split) ----
    {
        const int m = t & 15;
        const int p = t >> 4;                     // 16 K-partitions of 16
        float v0 = 0.f, v1 = 0.f;
        #pragma unroll
        for (int kk = 0; kk < 2; ++kk) {
            const int k0 = p * 16 + kk * 8;
            const short8 h = *(const short8*)&hs[m * S1 + k0];
            #pragma unroll
            for (int j = 0; j < 8; ++j) {
                const float hv = bs2f(h[j]);
                v0 = fmaf(hv, Wr3f[(k0 + j) * 2 + 0], v0);
                v1 = fmaf(hv, Wr3f[(k0 + j) * 2 + 1], v1);
            }
        }
        part[p][m][0] = v0;
        part[p][m][1] = v1;
    }
    __syncthreads();
    if (t < 2 * AG) {
        const int m = t >> 1, o = t & 1;
        float s = br3f[o] + barv;
        #pragma unroll
        for (int p = 0; p < 16; ++p) s += part[p][m][o];
        if (f32) ((float*)out)[a0 * 2 + t] = s;
        else     ((bf16*)out)[a0 * 2 + t] = __float2bfloat16(s);
    }
}

extern "C" void kernel_launch(void* const* d_in, const int* in_sizes, int n_in,
                              void* d_out, int out_size, void* d_ws, size_t ws_size,
                              hipStream_t stream)
{
    (void)in_sizes; (void)n_in; (void)out_size;

    const void* ef  = d_in[0];
    const int*  ids = (const int*)d_in[1];

    char* p = (char*)d_ws;
    int*   flag  = (int*)p;        p += 256;
    float* agg   = (float*)p;      p += (size_t)NA * 64 * 4;
    float* bar   = (float*)p;      p += (size_t)NA * 2 * 4;
    short* Wp1P  = (short*)p;      p += 8192 * 2;
    short* Wp2P  = (short*)p;      p += 65536 * 2;
    short* Wp3P  = (short*)p;      p += 32768 * 2;
    short* Wr1P  = (short*)p;      p += 16384 * 2;
    short* Wr2P  = (short*)p;      p += 65536 * 2;
    float* bp1f  = (float*)p;      p += 256 * 4;
    float* bp2f  = (float*)p;      p += 256 * 4;
    float* bp3f  = (float*)p;      p += 64 * 4;
    float* br1f  = (float*)p;      p += 256 * 4;
    float* br2f  = (float*)p;      p += 256 * 4;
    float* Wr3f  = (float*)p;      p += 512 * 4;
    float* br3f  = (float*)p;      p += 256;
    const size_t required = (size_t)(p - (char*)d_ws);
    if (ws_size < required) return;  // signature: output stays zero (absmax ~26)

    prep_weights_kernel<<<512, 256, 0, stream>>>(
        d_in[2], d_in[3], d_in[4], d_in[5], d_in[6], d_in[7],
        d_in[8], d_in[9], d_in[10], d_in[11], d_in[12], d_in[13],
        Wp1P, Wp2P, Wp3P, Wr1P, Wr2P,
        bp1f, bp2f, bp3f, br1f, br2f, Wr3f, br3f, agg, flag);
    edge_mlp_kernel<<<NE / E, 512, 0, stream>>>(
        ef, ids, Wp1P, bp1f, Wp2P, bp2f, Wp3P, bp3f, agg, bar, flag);
    agent_mlp_kernel<<<NA / AG, 256, 0, stream>>>(
        agg, bar, Wr1P, br1f, Wr2P, br2f, Wr3f, br3f, d_out, flag);
}